// Round 1
// baseline (156.808 us; speedup 1.0000x reference)
//
#include <hip/hip_runtime.h>

#define FD 128  // feature dim

// ---------------------------------------------------------------------------
// Kernel 1: u = z @ W   (z: [nrows, 128] fp32, W: [128,128] fp32)
// W staged in LDS (64 KB). Thread tile: 4 rows x 4 cols.
// Block 256 threads = 8 row-groups x 32 col-groups; block covers 32 rows.
// ---------------------------------------------------------------------------
__global__ __launch_bounds__(256, 2)
void bilinear_u_kernel(const float* __restrict__ z, const float* __restrict__ Wg,
                       float* __restrict__ u, int nrows) {
    __shared__ float Wl[FD * FD];  // 65536 bytes
    {
        const float4* s4 = (const float4*)Wg;
        float4* d4 = (float4*)Wl;
        #pragma unroll
        for (int i = 0; i < (FD * FD / 4) / 256; ++i)  // 16 iters
            d4[threadIdx.x + i * 256] = s4[threadIdx.x + i * 256];
    }
    __syncthreads();

    const int c  = (threadIdx.x & 31) << 2;   // column base: 0,4,...,124
    const int rg = threadIdx.x >> 5;          // row group 0..7
    const int rowbase = blockIdx.x * 32 + rg * 4;

    const int rc = nrows - 1;
    const float* zr0 = z + (size_t)(rowbase + 0 < rc ? rowbase + 0 : rc) * FD;
    const float* zr1 = z + (size_t)(rowbase + 1 < rc ? rowbase + 1 : rc) * FD;
    const float* zr2 = z + (size_t)(rowbase + 2 < rc ? rowbase + 2 : rc) * FD;
    const float* zr3 = z + (size_t)(rowbase + 3 < rc ? rowbase + 3 : rc) * FD;

    float4 a0 = {0.f, 0.f, 0.f, 0.f};
    float4 a1 = {0.f, 0.f, 0.f, 0.f};
    float4 a2 = {0.f, 0.f, 0.f, 0.f};
    float4 a3 = {0.f, 0.f, 0.f, 0.f};

#define BIL_STEP(ZC)                                                           \
    {                                                                          \
        a0.x += z0.ZC * w.x; a0.y += z0.ZC * w.y;                              \
        a0.z += z0.ZC * w.z; a0.w += z0.ZC * w.w;                              \
        a1.x += z1.ZC * w.x; a1.y += z1.ZC * w.y;                              \
        a1.z += z1.ZC * w.z; a1.w += z1.ZC * w.w;                              \
        a2.x += z2.ZC * w.x; a2.y += z2.ZC * w.y;                              \
        a2.z += z2.ZC * w.z; a2.w += z2.ZC * w.w;                              \
        a3.x += z3.ZC * w.x; a3.y += z3.ZC * w.y;                              \
        a3.z += z3.ZC * w.z; a3.w += z3.ZC * w.w;                              \
    }

    for (int d = 0; d < FD; d += 4) {
        float4 z0 = *(const float4*)(zr0 + d);
        float4 z1 = *(const float4*)(zr1 + d);
        float4 z2 = *(const float4*)(zr2 + d);
        float4 z3 = *(const float4*)(zr3 + d);
        float4 w;
        w = *(const float4*)&Wl[(d + 0) * FD + c]; BIL_STEP(x);
        w = *(const float4*)&Wl[(d + 1) * FD + c]; BIL_STEP(y);
        w = *(const float4*)&Wl[(d + 2) * FD + c]; BIL_STEP(z);
        w = *(const float4*)&Wl[(d + 3) * FD + c]; BIL_STEP(w);
    }
#undef BIL_STEP

    if (rowbase + 0 < nrows) *(float4*)&u[(size_t)(rowbase + 0) * FD + c] = a0;
    if (rowbase + 1 < nrows) *(float4*)&u[(size_t)(rowbase + 1) * FD + c] = a1;
    if (rowbase + 2 < nrows) *(float4*)&u[(size_t)(rowbase + 2) * FD + c] = a2;
    if (rowbase + 3 < nrows) *(float4*)&u[(size_t)(rowbase + 3) * FD + c] = a3;
}

// ---------------------------------------------------------------------------
// Kernel 2: out[e] = dot(u[src[e]], z[dst[e]]) + b
// 32 lanes per edge, float4 per lane (512 B row, fully coalesced).
// 2 edges per wave, 8 edges per 256-thread block.
// ---------------------------------------------------------------------------
__global__ __launch_bounds__(256)
void bilinear_edge_kernel(const float* __restrict__ u, const float* __restrict__ z,
                          const int* __restrict__ src, const int* __restrict__ dst,
                          const float* __restrict__ bias, float* __restrict__ out,
                          int E) {
    const int tid  = blockIdx.x * 256 + (int)threadIdx.x;
    const int wid  = tid >> 6;
    const int lane = (int)threadIdx.x & 63;
    const int half = lane >> 5;
    const int l    = lane & 31;
    const int e    = (wid << 1) | half;
    if (e >= E) return;

    const int s = src[e];
    const int t = dst[e];

    float4 a = ((const float4*)(u + (size_t)s * FD))[l];
    float4 b = ((const float4*)(z + (size_t)t * FD))[l];

    float sum = a.x * b.x + a.y * b.y + a.z * b.z + a.w * b.w;

    // reduce within each 32-lane half (xor offsets stay inside the half)
    #pragma unroll
    for (int off = 16; off >= 1; off >>= 1)
        sum += __shfl_xor(sum, off, 64);

    if (l == 0) out[e] = sum + bias[0];
}

// ---------------------------------------------------------------------------
// Fallback (only if workspace too small): fused per-edge bilinear.
// Block = 128 threads, one edge at a time, grid-stride. W in LDS.
// ---------------------------------------------------------------------------
__global__ __launch_bounds__(128)
void bilinear_fused_fallback(const float* __restrict__ z, const float* __restrict__ Wg,
                             const int* __restrict__ src, const int* __restrict__ dst,
                             const float* __restrict__ bias, float* __restrict__ out,
                             int E) {
    __shared__ float Wl[FD * FD];
    __shared__ float zs[FD];
    __shared__ float red[2];
    for (int i = threadIdx.x; i < FD * FD; i += 128) Wl[i] = Wg[i];
    __syncthreads();

    const int j = (int)threadIdx.x;
    for (int e = blockIdx.x; e < E; e += gridDim.x) {
        const int s = src[e];
        const int t = dst[e];
        zs[j] = z[(size_t)s * FD + j];
        __syncthreads();
        float acc = 0.f;
        #pragma unroll 8
        for (int d = 0; d < FD; ++d) acc += zs[d] * Wl[d * FD + j];
        float p = acc * z[(size_t)t * FD + j];
        #pragma unroll
        for (int off = 32; off >= 1; off >>= 1)
            p += __shfl_xor(p, off, 64);
        if ((j & 63) == 0) red[j >> 6] = p;
        __syncthreads();
        if (j == 0) out[e] = red[0] + red[1] + bias[0];
        __syncthreads();
    }
}

extern "C" void kernel_launch(void* const* d_in, const int* in_sizes, int n_in,
                              void* d_out, int out_size, void* d_ws, size_t ws_size,
                              hipStream_t stream) {
    const float* z    = (const float*)d_in[0];
    const int*   ei   = (const int*)d_in[1];
    const float* W    = (const float*)d_in[2];
    const float* bias = (const float*)d_in[3];
    float* out = (float*)d_out;

    const int nrows = in_sizes[0] / FD;
    const int E     = in_sizes[1] / 2;
    const int* src = ei;
    const int* dst = ei + E;

    const size_t need = (size_t)nrows * FD * sizeof(float);
    if (ws_size >= need) {
        float* u = (float*)d_ws;
        const int nb1 = (nrows + 31) / 32;
        bilinear_u_kernel<<<nb1, 256, 0, stream>>>(z, W, u, nrows);
        const int nb2 = (E + 7) / 8;
        bilinear_edge_kernel<<<nb2, 256, 0, stream>>>(u, z, src, dst, bias, out, E);
    } else {
        bilinear_fused_fallback<<<2048, 128, 0, stream>>>(z, W, src, dst, bias, out, E);
    }
}

// Round 2
// 85.036 us; speedup vs baseline: 1.8440x; 1.8440x over previous
//
#include <hip/hip_runtime.h>

#define FD 128  // feature dim

typedef __attribute__((ext_vector_type(8))) short short8;   // 8 bf16 = 4 VGPR
typedef __attribute__((ext_vector_type(4))) float f32x4;    // MFMA acc

__device__ __forceinline__ unsigned short f2bf(float f) {
    unsigned u = __float_as_uint(f);
    u += 0x7fff + ((u >> 16) & 1);   // round-to-nearest-even
    return (unsigned short)(u >> 16);
}
__device__ __forceinline__ float bfprod(unsigned a, unsigned b) {
    float a0 = __uint_as_float(a << 16);
    float a1 = __uint_as_float(a & 0xffff0000u);
    float b0 = __uint_as_float(b << 16);
    float b1 = __uint_as_float(b & 0xffff0000u);
    return __builtin_fmaf(a0, b0, a1 * b1);
}

// ---------------------------------------------------------------------------
// Kernel 0: Wt[n][k] = bf16(W[k][n])  (128x128). Coalesced reads, tiny.
// ---------------------------------------------------------------------------
__global__ void wt_kernel(const float* __restrict__ W, unsigned short* __restrict__ Wt) {
    const int idx = blockIdx.x * 256 + (int)threadIdx.x;  // 0..16383
    const int k = idx >> 7, n = idx & 127;
    Wt[n * FD + k] = f2bf(W[idx]);
}

// ---------------------------------------------------------------------------
// Kernel 1: u_bf16 = bf16(z @ W) via MFMA 16x16x32 bf16; also writes z_bf16.
// Block 256 threads = 4 waves; wave computes 32 rows x 128 cols.
// No LDS: B-frags from Wt (32 KB, L1/L2-cached); A-frags from fp32 z.
// A layout: lane l -> A[l&15][(l>>4)*8 + j]; B: lane l -> B[(l>>4)*8+j][l&15]
// D layout: lane l, reg r -> D[(l>>4)*4 + r][l&15]   [m89-verified]
// ---------------------------------------------------------------------------
__global__ __launch_bounds__(256)
void u_mfma_kernel(const float* __restrict__ z, const unsigned short* __restrict__ Wt,
                   unsigned short* __restrict__ u, unsigned short* __restrict__ zb,
                   int nrows) {
    const int lane = (int)threadIdx.x & 63;
    const int wave = (int)threadIdx.x >> 6;   // 0..3
    const int l16  = lane & 15;
    const int kq   = lane >> 4;               // 0..3
    const long rowbase = (long)blockIdx.x * 128 + wave * 32;

    f32x4 acc[2][8];
    #pragma unroll
    for (int mt = 0; mt < 2; ++mt)
        #pragma unroll
        for (int nt = 0; nt < 8; ++nt)
            acc[mt][nt] = (f32x4){0.f, 0.f, 0.f, 0.f};

    #pragma unroll
    for (int ks = 0; ks < 4; ++ks) {
        const int k0 = ks * 32 + kq * 8;

        short8 a[2];
        #pragma unroll
        for (int mt = 0; mt < 2; ++mt) {
            const long r  = rowbase + mt * 16 + l16;
            const long rc = (r < nrows) ? r : (long)(nrows - 1);
            const float4* zp = (const float4*)(z + rc * FD + k0);
            const float4 f0 = zp[0];
            const float4 f1 = zp[1];
            short8 av;
            av[0] = (short)f2bf(f0.x); av[1] = (short)f2bf(f0.y);
            av[2] = (short)f2bf(f0.z); av[3] = (short)f2bf(f0.w);
            av[4] = (short)f2bf(f1.x); av[5] = (short)f2bf(f1.y);
            av[6] = (short)f2bf(f1.z); av[7] = (short)f2bf(f1.w);
            a[mt] = av;
            if (r < nrows)
                *(short8*)(zb + r * FD + k0) = av;   // fused z->bf16 writeback
        }

        short8 b[8];
        #pragma unroll
        for (int nt = 0; nt < 8; ++nt)
            b[nt] = *(const short8*)(Wt + (size_t)(nt * 16 + l16) * FD + k0);

        #pragma unroll
        for (int mt = 0; mt < 2; ++mt)
            #pragma unroll
            for (int nt = 0; nt < 8; ++nt)
                acc[mt][nt] = __builtin_amdgcn_mfma_f32_16x16x32_bf16(
                    a[mt], b[nt], acc[mt][nt], 0, 0, 0);
    }

    #pragma unroll
    for (int mt = 0; mt < 2; ++mt)
        #pragma unroll
        for (int nt = 0; nt < 8; ++nt) {
            const f32x4 v = acc[mt][nt];
            #pragma unroll
            for (int r = 0; r < 4; ++r) {
                const long row = rowbase + mt * 16 + kq * 4 + r;
                if (row < nrows)
                    u[row * FD + nt * 16 + l16] = f2bf(v[r]);
            }
        }
}

// ---------------------------------------------------------------------------
// Kernel 2: out[e] = dot(u_bf16[src], z_bf16[dst]) + b
// 16 lanes per edge, 16 B (8 bf16) per lane; 4 edges/wave, 16 edges/block.
// ---------------------------------------------------------------------------
__global__ __launch_bounds__(256)
void edge_kernel_bf16(const unsigned short* __restrict__ u,
                      const unsigned short* __restrict__ zb,
                      const int* __restrict__ src, const int* __restrict__ dst,
                      const float* __restrict__ bias, float* __restrict__ out,
                      int E) {
    const int gw   = (blockIdx.x * 256 + (int)threadIdx.x) >> 6;
    const int lane = (int)threadIdx.x & 63;
    const int sub  = lane >> 4;      // edge slot within wave
    const int l16  = lane & 15;
    const int e    = gw * 4 + sub;
    if (e >= E) return;

    const int s = src[e];
    const int t = dst[e];

    const uint4 ua = ((const uint4*)(u  + (size_t)s * FD))[l16];
    const uint4 za = ((const uint4*)(zb + (size_t)t * FD))[l16];

    float sum = bfprod(ua.x, za.x) + bfprod(ua.y, za.y)
              + bfprod(ua.z, za.z) + bfprod(ua.w, za.w);

    #pragma unroll
    for (int off = 8; off >= 1; off >>= 1)
        sum += __shfl_xor(sum, off, 64);   // stays within the 16-lane group

    if (l16 == 0) out[e] = sum + bias[0];
}

// ---------------------------------------------------------------------------
// Fallback (workspace too small): fused per-edge bilinear, fp32.
// ---------------------------------------------------------------------------
__global__ __launch_bounds__(128)
void bilinear_fused_fallback(const float* __restrict__ z, const float* __restrict__ Wg,
                             const int* __restrict__ src, const int* __restrict__ dst,
                             const float* __restrict__ bias, float* __restrict__ out,
                             int E) {
    __shared__ float Wl[FD * FD];
    __shared__ float zs[FD];
    __shared__ float red[2];
    for (int i = threadIdx.x; i < FD * FD; i += 128) Wl[i] = Wg[i];
    __syncthreads();

    const int j = (int)threadIdx.x;
    for (int e = blockIdx.x; e < E; e += gridDim.x) {
        const int s = src[e];
        const int t = dst[e];
        zs[j] = z[(size_t)s * FD + j];
        __syncthreads();
        float acc = 0.f;
        #pragma unroll 8
        for (int d = 0; d < FD; ++d) acc += zs[d] * Wl[d * FD + j];
        float p = acc * z[(size_t)t * FD + j];
        #pragma unroll
        for (int off = 32; off >= 1; off >>= 1)
            p += __shfl_xor(p, off, 64);
        if ((j & 63) == 0) red[j >> 6] = p;
        __syncthreads();
        if (j == 0) out[e] = red[0] + red[1] + bias[0];
        __syncthreads();
    }
}

extern "C" void kernel_launch(void* const* d_in, const int* in_sizes, int n_in,
                              void* d_out, int out_size, void* d_ws, size_t ws_size,
                              hipStream_t stream) {
    const float* z    = (const float*)d_in[0];
    const int*   ei   = (const int*)d_in[1];
    const float* W    = (const float*)d_in[2];
    const float* bias = (const float*)d_in[3];
    float* out = (float*)d_out;

    const int nrows = in_sizes[0] / FD;
    const int E     = in_sizes[1] / 2;
    const int* src = ei;
    const int* dst = ei + E;

    const size_t need = (size_t)nrows * FD * 2 * sizeof(unsigned short); // u + zb
    if (ws_size >= need) {
        unsigned short* u  = (unsigned short*)d_ws;
        unsigned short* zb = u + (size_t)nrows * FD;
        // Stage Wt (32 KB bf16) in d_out; edge kernel fully overwrites d_out after.
        unsigned short* Wt = (unsigned short*)d_out;

        wt_kernel<<<64, 256, 0, stream>>>(W, Wt);
        const int nb1 = (nrows + 127) / 128;
        u_mfma_kernel<<<nb1, 256, 0, stream>>>(z, Wt, u, zb, nrows);
        const int nb2 = (E + 15) / 16;
        edge_kernel_bf16<<<nb2, 256, 0, stream>>>(u, zb, src, dst, bias, out, E);
    } else {
        bilinear_fused_fallback<<<2048, 128, 0, stream>>>(z, W, src, dst, bias, out, E);
    }
}